// Round 12
// baseline (4237.732 us; speedup 1.0000x reference)
//
#include <hip/hip_runtime.h>

#define EPI_PART 0
#define EPI_BF16D 1

#define T_ 40
#define VOC_ 10000

typedef __attribute__((ext_vector_type(8))) short bf16x8;
typedef __attribute__((ext_vector_type(4))) short short4v;
typedef __attribute__((ext_vector_type(8))) short short8v;
typedef __attribute__((ext_vector_type(4))) float float4v;
typedef __attribute__((ext_vector_type(4))) float f32x4;

__device__ __forceinline__ float bf2f(short s) {
  unsigned u = ((unsigned)(unsigned short)s) << 16;
  float f; __builtin_memcpy(&f, &u, 4); return f;
}
__device__ __forceinline__ short f2bf(float f) {
  unsigned u; __builtin_memcpy(&u, &f, 4);
  u += 0x7FFFu + ((u >> 16) & 1u);
  return (short)(u >> 16);
}
__device__ __forceinline__ float sigm(float x) { return 1.f / (1.f + expf(-x)); }

// packed W layout: W[row][k] at (row>>4)*16*K + (k>>3)*128 + (row&15)*8 + (k&7)
__device__ __forceinline__ size_t pkidx(int row, int k, int K) {
  return (size_t)(row >> 4) * 16 * K + (size_t)(k >> 3) * 128 + (size_t)((row & 15) * 8 + (k & 7));
}

// ---------------- packing kernels ----------------

__global__ __launch_bounds__(256) void k_f2bf_split(const float* __restrict__ s,
    short* __restrict__ dh, short* __restrict__ dl, long n4) {
  long i = (long)blockIdx.x * 256 + threadIdx.x;
  long stride = (long)gridDim.x * 256;
  for (; i < n4; i += stride) {
    float4v f = ((const float4v*)s)[i];
    short4v oh, ol;
    #pragma unroll
    for (int j = 0; j < 4; j++) {
      short h = f2bf(f[j]); oh[j] = h; ol[j] = f2bf(f[j] - bf2f(h));
    }
    ((short4v*)dh)[i] = oh;
    ((short4v*)dl)[i] = ol;
  }
}

__global__ __launch_bounds__(256) void k_permpk(short* __restrict__ dh, short* __restrict__ dl,
    const float* __restrict__ s1, int ld1, int col0, int K1,
    const float* __restrict__ s2, int ld2, int Ktot) {
  int K4 = Ktot >> 2;
  long n4 = 4096L * K4;
  long stride = (long)gridDim.x * 256;
  for (long i = (long)blockIdx.x * 256 + threadIdx.x; i < n4; i += stride) {
    int p = (int)(i / K4);
    int c = ((int)(i % K4)) << 2;
    int orig = ((p & 3) << 10) + (p >> 2);
    const float* src = (c < K1) ? (s1 + (long)orig * ld1 + col0 + c)
                                : (s2 + (long)orig * ld2 + (c - K1));
    float4v f = *(const float4v*)src;
    short4v oh, ol;
    #pragma unroll
    for (int j = 0; j < 4; j++) {
      short h = f2bf(f[j]); oh[j] = h; ol[j] = f2bf(f[j] - bf2f(h));
    }
    size_t d = pkidx(p, c, Ktot);
    *(short4v*)&dh[d] = oh;
    if (dl) *(short4v*)&dl[d] = ol;
  }
}

__global__ __launch_bounds__(256) void k_packpk(short* __restrict__ dh, short* __restrict__ dl,
    const float* __restrict__ src, int ld, int Nr, int Nsrc, int K) {
  int K4 = K >> 2;
  long n4 = (long)Nr * K4;
  long stride = (long)gridDim.x * 256;
  for (long i = (long)blockIdx.x * 256 + threadIdx.x; i < n4; i += stride) {
    int row = (int)(i / K4);
    int c = ((int)(i % K4)) << 2;
    float4v f = {0.f, 0.f, 0.f, 0.f};
    if (row < Nsrc) f = *(const float4v*)(src + (long)row * ld + c);
    short4v oh, ol;
    #pragma unroll
    for (int j = 0; j < 4; j++) {
      short h = f2bf(f[j]); oh[j] = h; ol[j] = f2bf(f[j] - bf2f(h));
    }
    size_t d = pkidx(row, c, K);
    *(short4v*)&dh[d] = oh;
    if (dl) *(short4v*)&dl[d] = ol;
  }
}

__global__ __launch_bounds__(256) void k_perm_bias(float* __restrict__ d1, const float* __restrict__ s1,
                                                   float* __restrict__ d2, const float* __restrict__ s2) {
  int p = blockIdx.x * 256 + threadIdx.x;
  if (p < 4096) {
    int orig = ((p & 3) << 10) + (p >> 2);
    d1[p] = s1[orig];
    d2[p] = s2[orig];
  }
}

__global__ __launch_bounds__(256) void k_gather_emb(short* __restrict__ dst, const float* __restrict__ embW,
                                                    const int* __restrict__ cap) {
  int i = blockIdx.x * 256 + threadIdx.x;  // 5120*128
  if (i >= 5120 * 128) return;
  int row = i >> 7, c8 = (i & 127) << 3;
  int tok = cap[row];
  const float4v* s = (const float4v*)(embW + (long)tok * 1024 + c8);
  float4v f0 = s[0], f1 = s[1];
  short8v o;
  #pragma unroll
  for (int j = 0; j < 4; j++) { o[j] = f2bf(f0[j]); o[4 + j] = f2bf(f1[j]); }
  *(short8v*)(dst + (long)row * 1024 + c8) = o;
}

// Wha f32 -> [hb 0..127][ph 0..255][8] packed
__global__ __launch_bounds__(256) void k_pack_whaf(float* __restrict__ dst, const float* __restrict__ Wha) {
  int i = blockIdx.x * 256 + threadIdx.x;  // 32768
  int hb = i >> 8, ph = i & 255;
  float4v a = *(const float4v*)(Wha + (long)ph * 1024 + hb * 8);
  float4v b4 = *(const float4v*)(Wha + (long)ph * 1024 + hb * 8 + 4);
  *(float4v*)(dst + ((long)hb * 256 + ph) * 8) = a;
  *(float4v*)(dst + ((long)hb * 256 + ph) * 8 + 4) = b4;
}

// ---------------- GEMM body: 4 waves x 2 n-frags (128-col tile), 64-k slabs ----------------
// kA0/kW0: independent k-offsets for A and W (enables W-slice GEMMs on packed W).
// sbase: partial-slot base (part slot = sbase + ks).

template<int NCS, bool SA, bool SW, int EPI>
__device__ __forceinline__ void gemm_body(short* sh, int bx, int ks, int mb,
    const short* __restrict__ A, const short* __restrict__ Alo, int lda,
    const short* __restrict__ W, const short* __restrict__ Wlo, int K,
    int kA0, int kW0, int sbase,
    int Npad, int Mtot, float* __restrict__ part, short* __restrict__ outbf) {
  const int tid = threadIdx.x;
  const int l = tid & 63, w = tid >> 6;
  const int rif = l & 15, kg = l >> 4;
  const int n0 = bx * 128;
  const int kloc = ks * NCS * 64;
  const int mbase = mb * 128;

  f32x4 acc[8][2];
  #pragma unroll
  for (int m = 0; m < 8; m++) {
    acc[m][0] = (f32x4){0.f, 0.f, 0.f, 0.f};
    acc[m][1] = (f32x4){0.f, 0.f, 0.f, 0.f};
  }

  bf16x8 wh[2][2][2], wl[2][2][2];    // [slot][sk][nf]
  size_t wt0 = (size_t)(n0 / 16 + w * 2) * 16 * K + (size_t)l * 8;
  size_t wt1 = wt0 + (size_t)16 * K;
  auto loadW = [&](int c, int slot) {
    size_t base = (size_t)((kW0 + kloc + c * 64) >> 3) * 128;
    #pragma unroll
    for (int sk = 0; sk < 2; sk++) {
      wh[slot][sk][0] = *(const bf16x8*)(W + wt0 + base + sk * 512);
      wh[slot][sk][1] = *(const bf16x8*)(W + wt1 + base + sk * 512);
      if (SW) {
        wl[slot][sk][0] = *(const bf16x8*)(Wlo + wt0 + base + sk * 512);
        wl[slot][sk][1] = *(const bf16x8*)(Wlo + wt1 + base + sk * 512);
      }
    }
  };

  short8v rA[4], rL[4];
  const int srow = tid >> 3;            // 0..31
  const int scol = (tid & 7) * 8;       // 0..56
  auto ldA = [&](int c) {
    #pragma unroll
    for (int j = 0; j < 4; j++) {
      size_t g = (size_t)(mbase + j * 32 + srow) * lda + kA0 + kloc + c * 64 + scol;
      rA[j] = *(const short8v*)(A + g);
      if (SA) rL[j] = *(const short8v*)(Alo + g);
    }
  };
  auto stA = [&]() {
    #pragma unroll
    for (int j = 0; j < 4; j++) {
      int row = j * 32 + srow;
      int idx = row * 64 + (scol ^ ((row & 7) << 3));
      *(short8v*)&sh[idx] = rA[j];
      if (SA) *(short8v*)&sh[8192 + idx] = rL[j];
    }
  };
  auto compute = [&](int slot) {
    #pragma unroll
    for (int sk = 0; sk < 2; sk++) {
      int colb = ((sk * 32 + kg * 8) ^ ((rif & 7) << 3));
      #pragma unroll
      for (int m = 0; m < 8; m++) {
        int idx = (m * 16 + rif) * 64 + colb;
        bf16x8 ah = *(const bf16x8*)&sh[idx];
        bf16x8 al;
        if (SA) al = *(const bf16x8*)&sh[8192 + idx];
        #pragma unroll
        for (int nf = 0; nf < 2; nf++) {
          acc[m][nf] = __builtin_amdgcn_mfma_f32_16x16x32_bf16(ah, wh[slot][sk][nf], acc[m][nf], 0, 0, 0);
          if (SA) acc[m][nf] = __builtin_amdgcn_mfma_f32_16x16x32_bf16(al, wh[slot][sk][nf], acc[m][nf], 0, 0, 0);
          if (SW) acc[m][nf] = __builtin_amdgcn_mfma_f32_16x16x32_bf16(ah, wl[slot][sk][nf], acc[m][nf], 0, 0, 0);
        }
      }
    }
  };

  ldA(0); loadW(0, 0);
  stA();
  __syncthreads();
  #pragma unroll
  for (int c = 0; c < NCS; c++) {
    if (c + 1 < NCS) { ldA(c + 1); loadW(c + 1, (c + 1) & 1); }
    compute(c & 1);
    __syncthreads();
    if (c + 1 < NCS) { stA(); __syncthreads(); }
  }

  #pragma unroll
  for (int nf = 0; nf < 2; nf++) {
    int colw = n0 + (w * 2 + nf) * 16 + rif;
    #pragma unroll
    for (int m = 0; m < 8; m++) {
      #pragma unroll
      for (int j = 0; j < 4; j++) {
        int row = m * 16 + kg * 4 + j;
        if constexpr (EPI == EPI_PART) {
          part[((size_t)(sbase + ks) * Mtot + mbase + row) * Npad + colw] = acc[m][nf][j];
        } else {
          outbf[(size_t)(mbase + row) * Npad + colw] = f2bf(acc[m][nf][j]);
        }
      }
    }
  }
}

// standalone GEMM kernel (pre-loop + G2b)
template<int NCS, bool SA, bool SW, int EPI>
__global__ __launch_bounds__(256) void k_g6(
    const short* __restrict__ A, const short* __restrict__ Alo, int lda,
    const short* __restrict__ W, const short* __restrict__ Wlo, int K,
    int Npad, int Mtot, float* __restrict__ part, short* __restrict__ outbf) {
  __shared__ short sh[SA ? 16384 : 8192];
  gemm_body<NCS, SA, SW, EPI>(sh, blockIdx.x, blockIdx.y, blockIdx.z,
      A, Alo, lda, W, Wlo, K, 0, 0, 0, Npad, Mtot, part, outbf);
}

// ---------------- partial sum (+bias) -> f32 ----------------
__global__ __launch_bounds__(256) void k_sum(const float* __restrict__ part,
    float* __restrict__ out, const float* __restrict__ bias,
    long n4, int N4, int KS, long stride4) {
  long i = (long)blockIdx.x * 256 + threadIdx.x;
  if (i >= n4) return;
  float4v a = *(const float4v*)&bias[(i % N4) * 4];
  for (int s = 0; s < KS; s++) {
    float4v p = ((const float4v*)part)[s * stride4 + i];
    #pragma unroll
    for (int j = 0; j < 4; j++) a[j] += p[j];
  }
  ((float4v*)out)[i] = a;
}

// ---------------- LSTM2 epilogue (sums 10 partials: G2b s0..7 + G2a s8..9) ----------------
__global__ __launch_bounds__(256) void k_epi2(
    const float* __restrict__ part, const float* __restrict__ b2p,
    float* __restrict__ cstate,
    const short* __restrict__ xcur_hi, const short* __restrict__ xcur_lo,
    short* __restrict__ xnext_hi, short* __restrict__ xnext_lo,
    short* __restrict__ h2n_hi, short* __restrict__ h2n_lo,
    const int* __restrict__ lengths, int t) {
  int i = blockIdx.x * 256 + threadIdx.x;   // 131072 = 128 b x 1024 h
  int b = i >> 10, h = i & 1023;
  float4v g = *(const float4v*)&b2p[h * 4];
  #pragma unroll
  for (int s = 0; s < 10; s++) {
    float4v p = *(const float4v*)&part[((size_t)s * 128 + b) * 4096 + h * 4];
    #pragma unroll
    for (int j = 0; j < 4; j++) g[j] += p[j];
  }
  float co = cstate[b * 1024 + h];
  float cn = sigm(g[1]) * co + sigm(g[0]) * tanhf(g[2]);
  float hn = sigm(g[3]) * tanhf(cn);
  bool act = lengths[b] > t;
  cstate[b * 1024 + h] = act ? cn : co;
  short hi16 = f2bf(hn);
  short lo16 = f2bf(hn - bf2f(hi16));
  h2n_hi[b * 1024 + h] = hi16;
  h2n_lo[b * 1024 + h] = lo16;
  short oh = xcur_hi[b * 2048 + h];
  short ol = xcur_lo[b * 2048 + h];
  xnext_hi[b * 2048 + h] = act ? hi16 : oh;
  xnext_lo[b * 2048 + h] = act ? lo16 : ol;
}

// ---------------- dual A: [G1 (t), KS=8] || [logits GEMM (t-1), KS=2] || [G2a (t), h2-part] --
__global__ __launch_bounds__(256) void k_dualA(
    const short* __restrict__ xcH, const short* __restrict__ xcL,
    const short* __restrict__ W1dHi, const short* __restrict__ W1dLo,
    float* __restrict__ partA,
    const short* __restrict__ h2nHi, const short* __restrict__ h2nLo,
    const short* __restrict__ WlPK, float* __restrict__ partLG,
    const short* __restrict__ W2dHi, const short* __restrict__ W2dLo, int t) {
  __shared__ short sh[16384];
  int bx = blockIdx.x;
  if (bx < 256) {
    if (t >= T_) return;
    gemm_body<4, true, true, EPI_PART>(sh, bx & 31, bx >> 5, 0,
        xcH, xcL, 2048, W1dHi, W1dLo, 2048, 0, 0, 0, 4096, 128, partA, nullptr);
  } else if (bx < 414) {
    if (t == 0) return;
    int f = bx - 256;                      // 0..157
    gemm_body<8, true, false, EPI_PART>(sh, f % 79, f / 79, 0,
        h2nHi, h2nLo, 1024, WlPK, nullptr, 1024, 0, 0, 0, 10112, 128, partLG, nullptr);
  } else {
    // G2a: gates2 h2-contribution. A = h2 state (x1 cols 0..1023), W = W2d cols 3072..4095.
    if (t >= T_) return;
    int f2 = bx - 414;                     // 0..63 = 32 col-tiles x KS=2
    gemm_body<8, true, true, EPI_PART>(sh, f2 & 31, f2 >> 5, 0,
        xcH, xcL, 2048, W2dHi, W2dLo, 4096, 0, 3072, 8, 4096, 128, partA, nullptr);
  }
}

// ---------------- dual B: [LSTM1-epi + ha + attention (t), 2 b/block] || [logits epi (t-1)] --
__global__ __launch_bounds__(256) void k_dualB(
    const float* __restrict__ partA,
    const float* __restrict__ zuv, const short* __restrict__ zemb,
    float* __restrict__ c1,
    const short* __restrict__ xcH, const short* __restrict__ xcL,
    short* __restrict__ xnH, short* __restrict__ xnL,
    short* __restrict__ x2H, short* __restrict__ x2L,
    const float* __restrict__ WhaF, const float* __restrict__ bha,
    const float* __restrict__ wa, const float* __restrict__ ba,
    const float* __restrict__ Va, const float* __restrict__ Vmat,
    const int* __restrict__ lengths,
    const float* __restrict__ partLG, const float* __restrict__ bl,
    float* __restrict__ out, int t) {
  __shared__ float h1f[2048];      // [bq][1024]
  __shared__ float ha_sh[512];     // [bq][256]
  __shared__ float wa_sh[256];
  __shared__ float logit_sh[80];   // [bq][40]
  __shared__ float p_sh[80];
  const int tid = threadIdx.x;
  if (blockIdx.x >= 64) {
    // logits epilogue for step t-1: sum 2 partials + bias + mask -> d_out
    if (t == 0) return;
    int id = (blockIdx.x - 64) * 256 + tid;   // 320000 = 128 b x 2500 col4
    if (id >= 320000) return;
    int b = id / 2500, q = (id % 2500) * 4;
    bool act = lengths[b] > (t - 1);
    float4v a = {0.f, 0.f, 0.f, 0.f};
    if (act) {
      a = *(const float4v*)&bl[q];
      #pragma unroll
      for (int s = 0; s < 2; s++) {
        float4v p = *(const float4v*)&partLG[((size_t)s * 128 + b) * 10112 + q];
        #pragma unroll
        for (int j = 0; j < 4; j++) a[j] += p[j];
      }
    }
    *(float4v*)&out[((size_t)b * T_ + (t - 1)) * VOC_ + q] = a;
    return;
  }
  if (t >= T_) return;
  const int b0 = blockIdx.x * 2;
  // phase A: LSTM1 epilogue (fixed s-order sum, KS=8), 2 b
  #pragma unroll
  for (int bq = 0; bq < 2; bq++) {
    const int b = b0 + bq;
    const bool act = lengths[b] > t;
    #pragma unroll
    for (int i = 0; i < 4; i++) {
      int h = i * 256 + tid;
      float4v g = {0.f, 0.f, 0.f, 0.f};
      #pragma unroll
      for (int s = 0; s < 8; s++) {
        float4v p = *(const float4v*)&partA[((size_t)s * 128 + b) * 4096 + h * 4];
        #pragma unroll
        for (int j = 0; j < 4; j++) g[j] += p[j];
      }
      float4v z = *(const float4v*)&zuv[(size_t)b * 4096 + h * 4];   // includes b1
      short4v e4 = *(const short4v*)&zemb[((size_t)b * T_ + t) * 4096 + h * 4];
      #pragma unroll
      for (int j = 0; j < 4; j++) g[j] += z[j] + bf2f(e4[j]);
      float co = c1[b * 1024 + h];
      float cn = sigm(g[1]) * co + sigm(g[0]) * tanhf(g[2]);
      float hn = sigm(g[3]) * tanhf(cn);
      c1[b * 1024 + h] = act ? cn : co;
      h1f[bq * 1024 + h] = hn;
      short hi16 = f2bf(hn);
      short lo16 = f2bf(hn - bf2f(hi16));
      x2H[b * 4096 + 2048 + h] = hi16;
      x2L[b * 4096 + 2048 + h] = lo16;
      short oh = xcH[b * 2048 + 1024 + h];
      short ol = xcL[b * 2048 + 1024 + h];
      xnH[b * 2048 + 1024 + h] = act ? hi16 : oh;
      xnL[b * 2048 + 1024 + h] = act ? lo16 : ol;
      // note: x2 h2-section no longer written — G2a consumes h2 directly from x1.
    }
  }
  wa_sh[tid] = wa[tid];
  __syncthreads();
  {  // phase B: ha[bq][ph=tid] — Wha streamed once, reused for 2 b
    float a0 = 0.f, a1 = 0.f;
    const float* wp = WhaF + tid * 8;
    #pragma unroll 4
    for (int hb = 0; hb < 128; hb++) {
      float4v w0 = *(const float4v*)(wp + (size_t)hb * 2048);
      float4v w1 = *(const float4v*)(wp + (size_t)hb * 2048 + 4);
      #pragma unroll
      for (int j = 0; j < 4; j++) {
        a0 += w0[j] * h1f[hb * 8 + j] + w1[j] * h1f[hb * 8 + 4 + j];
        a1 += w0[j] * h1f[1024 + hb * 8 + j] + w1[j] * h1f[1024 + hb * 8 + 4 + j];
      }
    }
    float bh = bha[tid];
    ha_sh[tid] = a0 + bh;
    ha_sh[256 + tid] = a1 + bh;
  }
  __syncthreads();
  {  // phase C: logit[bq][r]
    const int r0 = tid >> 3, sl = tid & 7;
    const float ba0 = ba[0];
    #pragma unroll
    for (int bq = 0; bq < 2; bq++) {
      for (int r = r0; r < 36; r += 32) {
        const float4v* va4 = (const float4v*)(Va + ((long)(b0 + bq) * 36 + r) * 256 + sl * 32);
        float part = 0.f;
        #pragma unroll
        for (int q = 0; q < 8; q++) {
          float4v v4 = va4[q];
          #pragma unroll
          for (int j = 0; j < 4; j++) {
            int ph = sl * 32 + q * 4 + j;
            part += tanhf(v4[j] + ha_sh[bq * 256 + ph]) * wa_sh[ph];
          }
        }
        part += __shfl_down(part, 4, 8);
        part += __shfl_down(part, 2, 8);
        part += __shfl_down(part, 1, 8);
        if (sl == 0) logit_sh[bq * 40 + r] = part + ba0;
      }
    }
  }
  __syncthreads();
  {  // phase D: softmax — waves 0,1 handle bq 0,1
    int wv = tid >> 6, ln = tid & 63;
    if (wv < 2) {
      float v = (ln < 36) ? logit_sh[wv * 40 + ln] : -3.4e38f;
      float m = v;
      #pragma unroll
      for (int o = 32; o > 0; o >>= 1) m = fmaxf(m, __shfl_xor(m, o));
      float e = (ln < 36) ? expf(v - m) : 0.f;
      float s = e;
      #pragma unroll
      for (int o = 32; o > 0; o >>= 1) s += __shfl_xor(s, o);
      if (ln < 36) p_sh[wv * 40 + ln] = e / s;
    }
  }
  __syncthreads();
  // phase E: av per bq (f32 exact) -> split hi/lo into x2
  #pragma unroll
  for (int bq = 0; bq < 2; bq++) {
    const int b = b0 + bq;
    float av[8];
    #pragma unroll
    for (int j = 0; j < 8; j++) av[j] = 0.f;
    const float* vb = Vmat + (long)b * (36 * 2048) + tid * 8;
    for (int r = 0; r < 36; r++) {
      float p = p_sh[bq * 40 + r];
      float4v v0 = *(const float4v*)(vb + (long)r * 2048);
      float4v v1 = *(const float4v*)(vb + (long)r * 2048 + 4);
      #pragma unroll
      for (int j = 0; j < 4; j++) { av[j] += p * v0[j]; av[4 + j] += p * v1[j]; }
    }
    short8v oh, ol;
    #pragma unroll
    for (int j = 0; j < 8; j++) {
      short h = f2bf(av[j]);
      oh[j] = h;
      ol[j] = f2bf(av[j] - bf2f(h));
    }
    *(short8v*)(x2H + b * 4096 + tid * 8) = oh;
    *(short8v*)(x2L + b * 4096 + tid * 8) = ol;
  }
}

// ---------------- host launcher ----------------
extern "C" void kernel_launch(void* const* d_in, const int* in_sizes, int n_in,
                              void* d_out, int out_size, void* d_ws, size_t ws_size,
                              hipStream_t stream) {
  const float* Vmat = (const float*)d_in[0];
  const float* uv   = (const float*)d_in[2];
  const int* captions = (const int*)d_in[3];
  const int* lengths  = (const int*)d_in[4];
  const float* embW = (const float*)d_in[5];
  const float* Wi1 = (const float*)d_in[6];
  const float* Wh1 = (const float*)d_in[7];
  const float* b1  = (const float*)d_in[8];
  const float* Wi2 = (const float*)d_in[9];
  const float* Wh2 = (const float*)d_in[10];
  const float* b2  = (const float*)d_in[11];
  const float* Wva = (const float*)d_in[12];
  const float* bva = (const float*)d_in[13];
  const float* Wha = (const float*)d_in[14];
  const float* bha = (const float*)d_in[15];
  const float* wa  = (const float*)d_in[16];
  const float* ba  = (const float*)d_in[17];
  const float* Wl  = (const float*)d_in[18];
  const float* bl  = (const float*)d_in[19];
  (void)in_sizes; (void)n_in; (void)out_size; (void)ws_size;

  char* ws = (char*)d_ws;
  size_t off = 0;
  auto alloc = [&](size_t bytes) { void* p = ws + off; off += (bytes + 255) & ~255UL; return p; };
  short* W1dHi = (short*)alloc(4096L * 2048 * 2);
  short* W1dLo = (short*)alloc(4096L * 2048 * 2);
  short* W2dHi = (short*)alloc(4096L * 4096 * 2);   // staging arena pre-loop
  short* W2dLo = (short*)alloc(4096L * 4096 * 2);
  short* WlPK  = (short*)alloc(10112L * 1024 * 2);  // packed, zero-padded rows 10000..10111
  float* WhaF  = (float*)alloc(128L * 256 * 8 * 4);
  float* VaBuf = (float*)alloc(4608L * 256 * 4);
  float* Z1uvB = (float*)alloc(128L * 4096 * 4);
  short* Z1embB = (short*)alloc(5120L * 4096 * 2);  // hosts Vmat hi/lo split pre-loop
  // partials arena: loop needs [10][128][4096] f32 = 21.0MB (G1/G2b s0..7, G2a s8..9);
  // pre-loop aliases (W1ePk 8.4MB + AembBF 10.5MB = 18.9MB) fit inside.
  float* partA = (float*)alloc(10L * 128 * 4096 * 4);
  float* partLG = (float*)alloc(2L * 128 * 10112 * 4); // 10.4MB (logits, KS=2)
  float* b1P = (float*)alloc(4096 * 4);
  float* b2P = (float*)alloc(4096 * 4);
  short* x1Hi = (short*)alloc(2L * 128 * 2048 * 2);
  short* x1Lo = (short*)alloc(2L * 128 * 2048 * 2);
  short* x2Hi = (short*)alloc(128L * 4096 * 2);     // [av | h1n | (unused)]
  short* x2Lo = (short*)alloc(128L * 4096 * 2);
  short* h2nHi = (short*)alloc(128L * 1024 * 2);
  short* h2nLo = (short*)alloc(128L * 1024 * 2);
  float* c1 = (float*)alloc(128L * 1024 * 4);
  float* c2 = (float*)alloc(128L * 1024 * 4);

  // aliased one-time regions
  short* W1uvHi = W2dHi;
  short* W1uvLo = W2dHi + 4096L * 2048;
  float* zuvPart = (float*)(W2dHi + 4096L * 4096);             // [8][128][4096] f32
  short* uvHi = W2dHi + 4096L * 4096 + 4096L * 2048 + 2097152;
  short* uvLo = uvHi + 128L * 2048;
  short* WvaHi = uvLo + 128L * 2048;
  short* WvaLo = WvaHi + 256L * 2048;
  float* vaPart = (float*)W2dHi;                               // [8][4608][256] after W1uv dead
  short* W1ePk = (short*)partA;                                // 8.4MB, dead before loop
  short* AembBF = (short*)partA + 4096L * 1024;                // 10.5MB, dead before loop
  short* VmatHi = Z1embB;
  short* VmatLo = Z1embB + 4608L * 2048;

  (void)hipMemsetAsync(x1Hi, 0, 2L * 128 * 2048 * 2, stream);
  (void)hipMemsetAsync(x1Lo, 0, 2L * 128 * 2048 * 2, stream);
  (void)hipMemsetAsync(c1, 0, 128L * 1024 * 4, stream);
  (void)hipMemsetAsync(c2, 0, 128L * 1024 * 4, stream);

  // ---- packing ----
  k_packpk<<<2048, 256, 0, stream>>>(WlPK, nullptr, Wl, 1024, 10112, 10000, 1024);
  k_pack_whaf<<<128, 256, 0, stream>>>(WhaF, Wha);
  k_packpk<<<512, 256, 0, stream>>>(WvaHi, WvaLo, Wva, 2048, 256, 256, 2048);
  k_permpk<<<2048, 256, 0, stream>>>(W1dHi, W1dLo, Wi1, 4096, 0, 1024, Wh1, 1024, 2048);
  k_permpk<<<2048, 256, 0, stream>>>(W1uvHi, W1uvLo, Wi1, 4096, 1024, 2048, Wi1, 4096, 2048);
  k_permpk<<<1024, 256, 0, stream>>>(W1ePk, nullptr, Wi1, 4096, 3072, 1024, Wi1, 4096, 1024);
  k_perm_bias<<<16, 256, 0, stream>>>(b1P, b1, b2P, b2);
  k_gather_emb<<<2560, 256, 0, stream>>>(AembBF, embW, captions);
  k_f2bf_split<<<2048, 256, 0, stream>>>(Vmat, VmatHi, VmatLo, 128L * 36 * 2048 / 4);
  k_f2bf_split<<<64, 256, 0, stream>>>(uv, uvHi, uvLo, 128L * 2048 / 4);

  // Z1uv = uv @ W1uv^T + b1 (perm): partials + sum
  k_g6<4, true, true, EPI_PART><<<dim3(32, 8, 1), 256, 0, stream>>>(
      uvHi, uvLo, 2048, W1uvHi, W1uvLo, 2048, 4096, 128, zuvPart, nullptr);
  k_sum<<<512, 256, 0, stream>>>(zuvPart, Z1uvB, b1P, 131072, 1024, 8, 131072);
  // Va = Vmat @ Wva^T + bva
  k_g6<4, true, true, EPI_PART><<<dim3(2, 8, 36), 256, 0, stream>>>(
      VmatHi, VmatLo, 2048, WvaHi, WvaLo, 2048, 256, 4608, vaPart, nullptr);
  k_sum<<<1152, 256, 0, stream>>>(vaPart, VaBuf, bva, 294912, 64, 8, 294912);
  // W2d pack (overwrites staging arena)
  k_permpk<<<4096, 256, 0, stream>>>(W2dHi, W2dLo, Wi2, 3072, 0, 3072, Wh2, 1024, 4096);
  // Z1emb = emb @ W1e^T -> bf16 direct (frees Vmat split region; W1ePk/Aemb die here)
  k_g6<16, false, false, EPI_BF16D><<<dim3(32, 1, 40), 256, 0, stream>>>(
      AembBF, nullptr, 1024, W1ePk, nullptr, 1024, 4096, 5120, nullptr, Z1embB);

  for (int t = 0; t <= T_; t++) {
    const short* xcH = x1Hi + (size_t)(t & 1) * (128 * 2048);
    const short* xcL = x1Lo + (size_t)(t & 1) * (128 * 2048);
    short* xnH = x1Hi + (size_t)((t + 1) & 1) * (128 * 2048);
    short* xnL = x1Lo + (size_t)((t + 1) & 1) * (128 * 2048);
    // D1: [G1(t) 256 blk] || [logits-GEMM(t-1) 158 blk] || [G2a(t) 64 blk, h2-part -> s8..9]
    k_dualA<<<478, 256, 0, stream>>>(xcH, xcL, W1dHi, W1dLo, partA,
        h2nHi, h2nLo, WlPK, partLG, W2dHi, W2dLo, t);
    // D2: [attn(t) 64 blk x 2b] || [logits-epilogue(t-1) 1250 blk]
    k_dualB<<<1314, 256, 0, stream>>>(partA, Z1uvB, Z1embB, c1,
        xcH, xcL, xnH, xnL, x2Hi, x2Lo, WhaF, bha, wa, ba, VaBuf, Vmat,
        lengths, partLG, bl, (float*)d_out, t);
    if (t < T_) {
      // D3: G2b (K=3072: av|h1n) partials s0..7 — 256 blocks
      k_g6<6, true, true, EPI_PART><<<dim3(32, 8, 1), 256, 0, stream>>>(
          x2Hi, x2Lo, 4096, W2dHi, W2dLo, 4096, 4096, 128, partA, nullptr);
      // D4: LSTM2 epilogue (sums s0..9)
      k_epi2<<<512, 256, 0, stream>>>(partA, b2P, c2,
          xcH, xcL, xnH, xnL, h2nHi, h2nLo, lengths, t);
    }
  }
}

// Round 13
// 3693.020 us; speedup vs baseline: 1.1475x; 1.1475x over previous
//
#include <hip/hip_runtime.h>

#define EPI_PART 0
#define EPI_BF16D 1

#define T_ 40
#define VOC_ 10000

typedef __attribute__((ext_vector_type(8))) short bf16x8;
typedef __attribute__((ext_vector_type(4))) short short4v;
typedef __attribute__((ext_vector_type(8))) short short8v;
typedef __attribute__((ext_vector_type(4))) float float4v;
typedef __attribute__((ext_vector_type(4))) float f32x4;

__device__ __forceinline__ float bf2f(short s) {
  unsigned u = ((unsigned)(unsigned short)s) << 16;
  float f; __builtin_memcpy(&f, &u, 4); return f;
}
__device__ __forceinline__ short f2bf(float f) {
  unsigned u; __builtin_memcpy(&u, &f, 4);
  u += 0x7FFFu + ((u >> 16) & 1u);
  return (short)(u >> 16);
}
__device__ __forceinline__ float sigm(float x) { return 1.f / (1.f + expf(-x)); }

// packed W layout: W[row][k] at (row>>4)*16*K + (k>>3)*128 + (row&15)*8 + (k&7)
__device__ __forceinline__ size_t pkidx(int row, int k, int K) {
  return (size_t)(row >> 4) * 16 * K + (size_t)(k >> 3) * 128 + (size_t)((row & 15) * 8 + (k & 7));
}

// ---------------- packing kernels ----------------

__global__ __launch_bounds__(256) void k_f2bf_split(const float* __restrict__ s,
    short* __restrict__ dh, short* __restrict__ dl, long n4) {
  long i = (long)blockIdx.x * 256 + threadIdx.x;
  long stride = (long)gridDim.x * 256;
  for (; i < n4; i += stride) {
    float4v f = ((const float4v*)s)[i];
    short4v oh, ol;
    #pragma unroll
    for (int j = 0; j < 4; j++) {
      short h = f2bf(f[j]); oh[j] = h; ol[j] = f2bf(f[j] - bf2f(h));
    }
    ((short4v*)dh)[i] = oh;
    ((short4v*)dl)[i] = ol;
  }
}

__global__ __launch_bounds__(256) void k_permpk(short* __restrict__ dh, short* __restrict__ dl,
    const float* __restrict__ s1, int ld1, int col0, int K1,
    const float* __restrict__ s2, int ld2, int Ktot) {
  int K4 = Ktot >> 2;
  long n4 = 4096L * K4;
  long stride = (long)gridDim.x * 256;
  for (long i = (long)blockIdx.x * 256 + threadIdx.x; i < n4; i += stride) {
    int p = (int)(i / K4);
    int c = ((int)(i % K4)) << 2;
    int orig = ((p & 3) << 10) + (p >> 2);
    const float* src = (c < K1) ? (s1 + (long)orig * ld1 + col0 + c)
                                : (s2 + (long)orig * ld2 + (c - K1));
    float4v f = *(const float4v*)src;
    short4v oh, ol;
    #pragma unroll
    for (int j = 0; j < 4; j++) {
      short h = f2bf(f[j]); oh[j] = h; ol[j] = f2bf(f[j] - bf2f(h));
    }
    size_t d = pkidx(p, c, Ktot);
    *(short4v*)&dh[d] = oh;
    if (dl) *(short4v*)&dl[d] = ol;
  }
}

__global__ __launch_bounds__(256) void k_packpk(short* __restrict__ dh, short* __restrict__ dl,
    const float* __restrict__ src, int ld, int Nr, int Nsrc, int K) {
  int K4 = K >> 2;
  long n4 = (long)Nr * K4;
  long stride = (long)gridDim.x * 256;
  for (long i = (long)blockIdx.x * 256 + threadIdx.x; i < n4; i += stride) {
    int row = (int)(i / K4);
    int c = ((int)(i % K4)) << 2;
    float4v f = {0.f, 0.f, 0.f, 0.f};
    if (row < Nsrc) f = *(const float4v*)(src + (long)row * ld + c);
    short4v oh, ol;
    #pragma unroll
    for (int j = 0; j < 4; j++) {
      short h = f2bf(f[j]); oh[j] = h; ol[j] = f2bf(f[j] - bf2f(h));
    }
    size_t d = pkidx(row, c, K);
    *(short4v*)&dh[d] = oh;
    if (dl) *(short4v*)&dl[d] = ol;
  }
}

__global__ __launch_bounds__(256) void k_perm_bias(float* __restrict__ d1, const float* __restrict__ s1,
                                                   float* __restrict__ d2, const float* __restrict__ s2) {
  int p = blockIdx.x * 256 + threadIdx.x;
  if (p < 4096) {
    int orig = ((p & 3) << 10) + (p >> 2);
    d1[p] = s1[orig];
    d2[p] = s2[orig];
  }
}

__global__ __launch_bounds__(256) void k_gather_emb(short* __restrict__ dst, const float* __restrict__ embW,
                                                    const int* __restrict__ cap) {
  int i = blockIdx.x * 256 + threadIdx.x;  // 5120*128
  if (i >= 5120 * 128) return;
  int row = i >> 7, c8 = (i & 127) << 3;
  int tok = cap[row];
  const float4v* s = (const float4v*)(embW + (long)tok * 1024 + c8);
  float4v f0 = s[0], f1 = s[1];
  short8v o;
  #pragma unroll
  for (int j = 0; j < 4; j++) { o[j] = f2bf(f0[j]); o[4 + j] = f2bf(f1[j]); }
  *(short8v*)(dst + (long)row * 1024 + c8) = o;
}

// Wha f32 -> [hb 0..127][ph 0..255][8] packed
__global__ __launch_bounds__(256) void k_pack_whaf(float* __restrict__ dst, const float* __restrict__ Wha) {
  int i = blockIdx.x * 256 + threadIdx.x;  // 32768
  int hb = i >> 8, ph = i & 255;
  float4v a = *(const float4v*)(Wha + (long)ph * 1024 + hb * 8);
  float4v b4 = *(const float4v*)(Wha + (long)ph * 1024 + hb * 8 + 4);
  *(float4v*)(dst + ((long)hb * 256 + ph) * 8) = a;
  *(float4v*)(dst + ((long)hb * 256 + ph) * 8 + 4) = b4;
}

// ---------------- GEMM body: 4 waves x 2 n-frags (128-col tile), 64-k slabs ----------------

template<int NCS, bool SA, bool SW, int EPI>
__device__ __forceinline__ void gemm_body(short* sh, int bx, int ks, int mb,
    const short* __restrict__ A, const short* __restrict__ Alo, int lda,
    const short* __restrict__ W, const short* __restrict__ Wlo, int K,
    int Npad, int Mtot, float* __restrict__ part, short* __restrict__ outbf) {
  const int tid = threadIdx.x;
  const int l = tid & 63, w = tid >> 6;
  const int rif = l & 15, kg = l >> 4;
  const int n0 = bx * 128;
  const int k0 = ks * NCS * 64;
  const int mbase = mb * 128;

  f32x4 acc[8][2];
  #pragma unroll
  for (int m = 0; m < 8; m++) {
    acc[m][0] = (f32x4){0.f, 0.f, 0.f, 0.f};
    acc[m][1] = (f32x4){0.f, 0.f, 0.f, 0.f};
  }

  bf16x8 wh[2][2][2], wl[2][2][2];    // [slot][sk][nf]
  size_t wt0 = (size_t)(n0 / 16 + w * 2) * 16 * K + (size_t)l * 8;
  size_t wt1 = wt0 + (size_t)16 * K;
  auto loadW = [&](int c, int slot) {
    size_t base = (size_t)((k0 + c * 64) >> 3) * 128;
    #pragma unroll
    for (int sk = 0; sk < 2; sk++) {
      wh[slot][sk][0] = *(const bf16x8*)(W + wt0 + base + sk * 512);
      wh[slot][sk][1] = *(const bf16x8*)(W + wt1 + base + sk * 512);
      if (SW) {
        wl[slot][sk][0] = *(const bf16x8*)(Wlo + wt0 + base + sk * 512);
        wl[slot][sk][1] = *(const bf16x8*)(Wlo + wt1 + base + sk * 512);
      }
    }
  };

  short8v rA[4], rL[4];
  const int srow = tid >> 3;            // 0..31
  const int scol = (tid & 7) * 8;       // 0..56
  auto ldA = [&](int c) {
    #pragma unroll
    for (int j = 0; j < 4; j++) {
      size_t g = (size_t)(mbase + j * 32 + srow) * lda + k0 + c * 64 + scol;
      rA[j] = *(const short8v*)(A + g);
      if (SA) rL[j] = *(const short8v*)(Alo + g);
    }
  };
  auto stA = [&]() {
    #pragma unroll
    for (int j = 0; j < 4; j++) {
      int row = j * 32 + srow;
      int idx = row * 64 + (scol ^ ((row & 7) << 3));
      *(short8v*)&sh[idx] = rA[j];
      if (SA) *(short8v*)&sh[8192 + idx] = rL[j];
    }
  };
  auto compute = [&](int slot) {
    #pragma unroll
    for (int sk = 0; sk < 2; sk++) {
      int colb = ((sk * 32 + kg * 8) ^ ((rif & 7) << 3));
      #pragma unroll
      for (int m = 0; m < 8; m++) {
        int idx = (m * 16 + rif) * 64 + colb;
        bf16x8 ah = *(const bf16x8*)&sh[idx];
        bf16x8 al;
        if (SA) al = *(const bf16x8*)&sh[8192 + idx];
        #pragma unroll
        for (int nf = 0; nf < 2; nf++) {
          acc[m][nf] = __builtin_amdgcn_mfma_f32_16x16x32_bf16(ah, wh[slot][sk][nf], acc[m][nf], 0, 0, 0);
          if (SA) acc[m][nf] = __builtin_amdgcn_mfma_f32_16x16x32_bf16(al, wh[slot][sk][nf], acc[m][nf], 0, 0, 0);
          if (SW) acc[m][nf] = __builtin_amdgcn_mfma_f32_16x16x32_bf16(ah, wl[slot][sk][nf], acc[m][nf], 0, 0, 0);
        }
      }
    }
  };

  ldA(0); loadW(0, 0);
  stA();
  __syncthreads();
  #pragma unroll
  for (int c = 0; c < NCS; c++) {
    if (c + 1 < NCS) { ldA(c + 1); loadW(c + 1, (c + 1) & 1); }
    compute(c & 1);
    __syncthreads();
    if (c + 1 < NCS) { stA(); __syncthreads(); }
  }

  #pragma unroll
  for (int nf = 0; nf < 2; nf++) {
    int colw = n0 + (w * 2 + nf) * 16 + rif;
    #pragma unroll
    for (int m = 0; m < 8; m++) {
      #pragma unroll
      for (int j = 0; j < 4; j++) {
        int row = m * 16 + kg * 4 + j;
        if constexpr (EPI == EPI_PART) {
          part[((size_t)ks * Mtot + mbase + row) * Npad + colw] = acc[m][nf][j];
        } else {
          outbf[(size_t)(mbase + row) * Npad + colw] = f2bf(acc[m][nf][j]);
        }
      }
    }
  }
}

// standalone GEMM kernel (pre-loop + G2)
template<int NCS, bool SA, bool SW, int EPI>
__global__ __launch_bounds__(256) void k_g6(
    const short* __restrict__ A, const short* __restrict__ Alo, int lda,
    const short* __restrict__ W, const short* __restrict__ Wlo, int K,
    int Npad, int Mtot, float* __restrict__ part, short* __restrict__ outbf) {
  __shared__ short sh[SA ? 16384 : 8192];
  gemm_body<NCS, SA, SW, EPI>(sh, blockIdx.x, blockIdx.y, blockIdx.z,
      A, Alo, lda, W, Wlo, K, Npad, Mtot, part, outbf);
}

// ---------------- partial sum (+bias) -> f32 ----------------
__global__ __launch_bounds__(256) void k_sum(const float* __restrict__ part,
    float* __restrict__ out, const float* __restrict__ bias,
    long n4, int N4, int KS, long stride4) {
  long i = (long)blockIdx.x * 256 + threadIdx.x;
  if (i >= n4) return;
  float4v a = *(const float4v*)&bias[(i % N4) * 4];
  for (int s = 0; s < KS; s++) {
    float4v p = ((const float4v*)part)[s * stride4 + i];
    #pragma unroll
    for (int j = 0; j < 4; j++) a[j] += p[j];
  }
  ((float4v*)out)[i] = a;
}

// ---------------- LSTM2 epilogue ----------------
__global__ __launch_bounds__(256) void k_epi2(
    const float* __restrict__ part, const float* __restrict__ b2p,
    float* __restrict__ cstate,
    const short* __restrict__ xcur_hi, const short* __restrict__ xcur_lo,
    short* __restrict__ xnext_hi, short* __restrict__ xnext_lo,
    short* __restrict__ h2n_hi, short* __restrict__ h2n_lo,
    const int* __restrict__ lengths, int t) {
  int i = blockIdx.x * 256 + threadIdx.x;   // 131072 = 128 b x 1024 h
  int b = i >> 10, h = i & 1023;
  float4v g = *(const float4v*)&b2p[h * 4];
  #pragma unroll
  for (int s = 0; s < 8; s++) {
    float4v p = *(const float4v*)&part[((size_t)s * 128 + b) * 4096 + h * 4];
    #pragma unroll
    for (int j = 0; j < 4; j++) g[j] += p[j];
  }
  float co = cstate[b * 1024 + h];
  float cn = sigm(g[1]) * co + sigm(g[0]) * tanhf(g[2]);
  float hn = sigm(g[3]) * tanhf(cn);
  bool act = lengths[b] > t;
  cstate[b * 1024 + h] = act ? cn : co;
  short hi16 = f2bf(hn);
  short lo16 = f2bf(hn - bf2f(hi16));
  h2n_hi[b * 1024 + h] = hi16;
  h2n_lo[b * 1024 + h] = lo16;
  short oh = xcur_hi[b * 2048 + h];
  short ol = xcur_lo[b * 2048 + h];
  xnext_hi[b * 2048 + h] = act ? hi16 : oh;
  xnext_lo[b * 2048 + h] = act ? lo16 : ol;
}

// ---------------- dual A: [G1 GEMM (t), KS=8] || [logits GEMM (t-1), KS=2] ----------------
__global__ __launch_bounds__(256) void k_dualA(
    const short* __restrict__ xcH, const short* __restrict__ xcL,
    const short* __restrict__ W1dHi, const short* __restrict__ W1dLo,
    float* __restrict__ partA,
    const short* __restrict__ h2nHi, const short* __restrict__ h2nLo,
    const short* __restrict__ WlPK, float* __restrict__ partLG, int t) {
  __shared__ short sh[16384];
  int bx = blockIdx.x;
  if (bx < 256) {
    if (t >= T_) return;
    gemm_body<4, true, true, EPI_PART>(sh, bx & 31, bx >> 5, 0,
        xcH, xcL, 2048, W1dHi, W1dLo, 2048, 4096, 128, partA, nullptr);
  } else {
    if (t == 0) return;
    int f = bx - 256;                      // 0..157
    gemm_body<8, true, false, EPI_PART>(sh, f % 79, f / 79, 0,
        h2nHi, h2nLo, 1024, WlPK, nullptr, 1024, 10112, 128, partLG, nullptr);
  }
}

// ---------------- dual B: [LSTM1-epi + ha + attention (t)] || [logits epilogue (t-1)] -------
__global__ __launch_bounds__(256) void k_dualB(
    const float* __restrict__ partA,
    const float* __restrict__ zuv, const short* __restrict__ zemb,
    float* __restrict__ c1,
    const short* __restrict__ xcH, const short* __restrict__ xcL,
    short* __restrict__ xnH, short* __restrict__ xnL,
    short* __restrict__ x2H, short* __restrict__ x2L,
    const float* __restrict__ WhaF, const float* __restrict__ bha,
    const float* __restrict__ wa, const float* __restrict__ ba,
    const float* __restrict__ Va, const float* __restrict__ Vmat,
    const int* __restrict__ lengths,
    const float* __restrict__ partLG, const float* __restrict__ bl,
    float* __restrict__ out, int t) {
  __shared__ float h1f[1024];
  __shared__ float ha_sh[256];
  __shared__ float wa_sh[256];
  __shared__ float logit_sh[40];
  __shared__ float p_sh[40];
  const int tid = threadIdx.x;
  if (blockIdx.x >= 128) {
    // logits epilogue for step t-1: sum 2 partials + bias + mask -> d_out
    if (t == 0) return;
    int id = (blockIdx.x - 128) * 256 + tid;   // 320000 = 128 b x 2500 col4
    if (id >= 320000) return;
    int b = id / 2500, q = (id % 2500) * 4;
    bool act = lengths[b] > (t - 1);
    float4v a = {0.f, 0.f, 0.f, 0.f};
    if (act) {
      a = *(const float4v*)&bl[q];
      #pragma unroll
      for (int s = 0; s < 2; s++) {
        float4v p = *(const float4v*)&partLG[((size_t)s * 128 + b) * 10112 + q];
        #pragma unroll
        for (int j = 0; j < 4; j++) a[j] += p[j];
      }
    }
    *(float4v*)&out[((size_t)b * T_ + (t - 1)) * VOC_ + q] = a;
    return;
  }
  if (t >= T_) return;
  const int b = blockIdx.x;
  const bool act = lengths[b] > t;
  // LSTM1 epilogue (fixed s-order sum, KS=8)
  #pragma unroll
  for (int i = 0; i < 4; i++) {
    int h = i * 256 + tid;
    float4v g = {0.f, 0.f, 0.f, 0.f};
    #pragma unroll
    for (int s = 0; s < 8; s++) {
      float4v p = *(const float4v*)&partA[((size_t)s * 128 + b) * 4096 + h * 4];
      #pragma unroll
      for (int j = 0; j < 4; j++) g[j] += p[j];
    }
    float4v z = *(const float4v*)&zuv[(size_t)b * 4096 + h * 4];   // includes b1
    short4v e4 = *(const short4v*)&zemb[((size_t)b * T_ + t) * 4096 + h * 4];
    #pragma unroll
    for (int j = 0; j < 4; j++) g[j] += z[j] + bf2f(e4[j]);
    float co = c1[b * 1024 + h];
    float cn = sigm(g[1]) * co + sigm(g[0]) * tanhf(g[2]);
    float hn = sigm(g[3]) * tanhf(cn);
    c1[b * 1024 + h] = act ? cn : co;
    h1f[h] = hn;
    short hi16 = f2bf(hn);
    short lo16 = f2bf(hn - bf2f(hi16));
    x2H[b * 4096 + 2048 + h] = hi16;
    x2L[b * 4096 + 2048 + h] = lo16;
    short oh = xcH[b * 2048 + 1024 + h];
    short ol = xcL[b * 2048 + 1024 + h];
    xnH[b * 2048 + 1024 + h] = act ? hi16 : oh;
    xnL[b * 2048 + 1024 + h] = act ? lo16 : ol;
    x2H[b * 4096 + 3072 + h] = xcH[b * 2048 + h];
    x2L[b * 4096 + 3072 + h] = xcL[b * 2048 + h];
  }
  wa_sh[tid] = wa[tid];
  __syncthreads();
  {  // ha[ph] = Wha[ph,:] . h1n + bha[ph]
    float a = 0.f;
    const float* wp = WhaF + tid * 8;
    #pragma unroll 4
    for (int hb = 0; hb < 128; hb++) {
      float4v w0 = *(const float4v*)(wp + (size_t)hb * 2048);
      float4v w1 = *(const float4v*)(wp + (size_t)hb * 2048 + 4);
      #pragma unroll
      for (int j = 0; j < 4; j++) a += w0[j] * h1f[hb * 8 + j] + w1[j] * h1f[hb * 8 + 4 + j];
    }
    ha_sh[tid] = a + bha[tid];
  }
  __syncthreads();
  {  // logit[r]
    const int r0 = tid >> 3, sl = tid & 7;
    const float ba0 = ba[0];
    for (int r = r0; r < 36; r += 32) {
      const float4v* va4 = (const float4v*)(Va + ((long)b * 36 + r) * 256 + sl * 32);
      float part = 0.f;
      #pragma unroll
      for (int q = 0; q < 8; q++) {
        float4v v4 = va4[q];
        #pragma unroll
        for (int j = 0; j < 4; j++) {
          int ph = sl * 32 + q * 4 + j;
          part += tanhf(v4[j] + ha_sh[ph]) * wa_sh[ph];
        }
      }
      part += __shfl_down(part, 4, 8);
      part += __shfl_down(part, 2, 8);
      part += __shfl_down(part, 1, 8);
      if (sl == 0) logit_sh[r] = part + ba0;
    }
  }
  __syncthreads();
  if (tid < 64) {  // softmax over R=36
    float v = (tid < 36) ? logit_sh[tid] : -3.4e38f;
    float m = v;
    #pragma unroll
    for (int off = 32; off > 0; off >>= 1) m = fmaxf(m, __shfl_xor(m, off));
    float e = (tid < 36) ? expf(v - m) : 0.f;
    float s = e;
    #pragma unroll
    for (int off = 32; off > 0; off >>= 1) s += __shfl_xor(s, off);
    if (tid < 36) p_sh[tid] = e / s;
  }
  __syncthreads();
  {  // av (f32 exact) -> split hi/lo into x2
    float av[8];
    #pragma unroll
    for (int j = 0; j < 8; j++) av[j] = 0.f;
    const float* vb = Vmat + (long)b * (36 * 2048) + tid * 8;
    for (int r = 0; r < 36; r++) {
      float p = p_sh[r];
      float4v v0 = *(const float4v*)(vb + (long)r * 2048);
      float4v v1 = *(const float4v*)(vb + (long)r * 2048 + 4);
      #pragma unroll
      for (int j = 0; j < 4; j++) { av[j] += p * v0[j]; av[4 + j] += p * v1[j]; }
    }
    short8v oh, ol;
    #pragma unroll
    for (int j = 0; j < 8; j++) {
      short h = f2bf(av[j]);
      oh[j] = h;
      ol[j] = f2bf(av[j] - bf2f(h));
    }
    *(short8v*)(x2H + b * 4096 + tid * 8) = oh;
    *(short8v*)(x2L + b * 4096 + tid * 8) = ol;
  }
}

// ---------------- host launcher ----------------
extern "C" void kernel_launch(void* const* d_in, const int* in_sizes, int n_in,
                              void* d_out, int out_size, void* d_ws, size_t ws_size,
                              hipStream_t stream) {
  const float* Vmat = (const float*)d_in[0];
  const float* uv   = (const float*)d_in[2];
  const int* captions = (const int*)d_in[3];
  const int* lengths  = (const int*)d_in[4];
  const float* embW = (const float*)d_in[5];
  const float* Wi1 = (const float*)d_in[6];
  const float* Wh1 = (const float*)d_in[7];
  const float* b1  = (const float*)d_in[8];
  const float* Wi2 = (const float*)d_in[9];
  const float* Wh2 = (const float*)d_in[10];
  const float* b2  = (const float*)d_in[11];
  const float* Wva = (const float*)d_in[12];
  const float* bva = (const float*)d_in[13];
  const float* Wha = (const float*)d_in[14];
  const float* bha = (const float*)d_in[15];
  const float* wa  = (const float*)d_in[16];
  const float* ba  = (const float*)d_in[17];
  const float* Wl  = (const float*)d_in[18];
  const float* bl  = (const float*)d_in[19];
  (void)in_sizes; (void)n_in; (void)out_size; (void)ws_size;

  char* ws = (char*)d_ws;
  size_t off = 0;
  auto alloc = [&](size_t bytes) { void* p = ws + off; off += (bytes + 255) & ~255UL; return p; };
  short* W1dHi = (short*)alloc(4096L * 2048 * 2);
  short* W1dLo = (short*)alloc(4096L * 2048 * 2);
  short* W2dHi = (short*)alloc(4096L * 4096 * 2);   // staging arena pre-loop
  short* W2dLo = (short*)alloc(4096L * 4096 * 2);
  short* WlPK  = (short*)alloc(10112L * 1024 * 2);  // packed, zero-padded rows 10000..10111
  float* WhaF  = (float*)alloc(128L * 256 * 8 * 4);
  float* VaBuf = (float*)alloc(4608L * 256 * 4);
  float* Z1uvB = (float*)alloc(128L * 4096 * 4);
  short* Z1embB = (short*)alloc(5120L * 4096 * 2);  // hosts Vmat hi/lo split pre-loop
  float* partA = (float*)alloc(8L * 128 * 4096 * 4);   // 16.8MB (G1/G2)
  float* partLG = (float*)alloc(2L * 128 * 10112 * 4); // 10.4MB (logits, KS=2)
  float* b1P = (float*)alloc(4096 * 4);
  float* b2P = (float*)alloc(4096 * 4);
  short* x1Hi = (short*)alloc(2L * 128 * 2048 * 2);
  short* x1Lo = (short*)alloc(2L * 128 * 2048 * 2);
  short* x2Hi = (short*)alloc(128L * 4096 * 2);     // [av | h1n | h2]
  short* x2Lo = (short*)alloc(128L * 4096 * 2);
  short* h2nHi = (short*)alloc(128L * 1024 * 2);
  short* h2nLo = (short*)alloc(128L * 1024 * 2);
  float* c1 = (float*)alloc(128L * 1024 * 4);
  float* c2 = (float*)alloc(128L * 1024 * 4);

  // aliased one-time regions
  short* W1uvHi = W2dHi;
  short* W1uvLo = W2dHi + 4096L * 2048;
  float* zuvPart = (float*)(W2dHi + 4096L * 4096);             // [8][128][4096] f32
  short* uvHi = W2dHi + 4096L * 4096 + 4096L * 2048 + 2097152;
  short* uvLo = uvHi + 128L * 2048;
  short* WvaHi = uvLo + 128L * 2048;
  short* WvaLo = WvaHi + 256L * 2048;
  float* vaPart = (float*)W2dHi;                               // [8][4608][256] after W1uv dead
  short* W1ePk = (short*)partA;                                // 8.4MB, dead before loop
  short* AembBF = (short*)partA + 4096L * 1024;                // 10.5MB (spans into partLG), dead before loop
  short* VmatHi = Z1embB;
  short* VmatLo = Z1embB + 4608L * 2048;

  (void)hipMemsetAsync(x1Hi, 0, 2L * 128 * 2048 * 2, stream);
  (void)hipMemsetAsync(x1Lo, 0, 2L * 128 * 2048 * 2, stream);
  (void)hipMemsetAsync(c1, 0, 128L * 1024 * 4, stream);
  (void)hipMemsetAsync(c2, 0, 128L * 1024 * 4, stream);

  // ---- packing ----
  k_packpk<<<2048, 256, 0, stream>>>(WlPK, nullptr, Wl, 1024, 10112, 10000, 1024);
  k_pack_whaf<<<128, 256, 0, stream>>>(WhaF, Wha);
  k_packpk<<<512, 256, 0, stream>>>(WvaHi, WvaLo, Wva, 2048, 256, 256, 2048);
  k_permpk<<<2048, 256, 0, stream>>>(W1dHi, W1dLo, Wi1, 4096, 0, 1024, Wh1, 1024, 2048);
  k_permpk<<<2048, 256, 0, stream>>>(W1uvHi, W1uvLo, Wi1, 4096, 1024, 2048, Wi1, 4096, 2048);
  k_permpk<<<1024, 256, 0, stream>>>(W1ePk, nullptr, Wi1, 4096, 3072, 1024, Wi1, 4096, 1024);
  k_perm_bias<<<16, 256, 0, stream>>>(b1P, b1, b2P, b2);
  k_gather_emb<<<2560, 256, 0, stream>>>(AembBF, embW, captions);
  k_f2bf_split<<<2048, 256, 0, stream>>>(Vmat, VmatHi, VmatLo, 128L * 36 * 2048 / 4);
  k_f2bf_split<<<64, 256, 0, stream>>>(uv, uvHi, uvLo, 128L * 2048 / 4);

  // Z1uv = uv @ W1uv^T + b1 (perm): partials + sum
  k_g6<4, true, true, EPI_PART><<<dim3(32, 8, 1), 256, 0, stream>>>(
      uvHi, uvLo, 2048, W1uvHi, W1uvLo, 2048, 4096, 128, zuvPart, nullptr);
  k_sum<<<512, 256, 0, stream>>>(zuvPart, Z1uvB, b1P, 131072, 1024, 8, 131072);
  // Va = Vmat @ Wva^T + bva
  k_g6<4, true, true, EPI_PART><<<dim3(2, 8, 36), 256, 0, stream>>>(
      VmatHi, VmatLo, 2048, WvaHi, WvaLo, 2048, 256, 4608, vaPart, nullptr);
  k_sum<<<1152, 256, 0, stream>>>(vaPart, VaBuf, bva, 294912, 64, 8, 294912);
  // W2d pack (overwrites staging arena)
  k_permpk<<<4096, 256, 0, stream>>>(W2dHi, W2dLo, Wi2, 3072, 0, 3072, Wh2, 1024, 4096);
  // Z1emb = emb @ W1e^T -> bf16 direct (frees Vmat split region; W1ePk/Aemb die here)
  k_g6<16, false, false, EPI_BF16D><<<dim3(32, 1, 40), 256, 0, stream>>>(
      AembBF, nullptr, 1024, W1ePk, nullptr, 1024, 4096, 5120, nullptr, Z1embB);

  for (int t = 0; t <= T_; t++) {
    const short* xcH = x1Hi + (size_t)(t & 1) * (128 * 2048);
    const short* xcL = x1Lo + (size_t)(t & 1) * (128 * 2048);
    short* xnH = x1Hi + (size_t)((t + 1) & 1) * (128 * 2048);
    short* xnL = x1Lo + (size_t)((t + 1) & 1) * (128 * 2048);
    // D1: [G1(t) 256 blocks KS=8] || [logits-GEMM(t-1) 158 blocks KS=2]
    k_dualA<<<414, 256, 0, stream>>>(xcH, xcL, W1dHi, W1dLo, partA,
        h2nHi, h2nLo, WlPK, partLG, t);
    // D2: [attn(t) 128 blocks] || [logits-epilogue(t-1) 1250 blocks]
    k_dualB<<<1378, 256, 0, stream>>>(partA, Z1uvB, Z1embB, c1,
        xcH, xcL, xnH, xnL, x2Hi, x2Lo, WhaF, bha, wa, ba, VaBuf, Vmat,
        lengths, partLG, bl, (float*)d_out, t);
    if (t < T_) {
      // D3: G2 partials [8][128][4096] — 256 blocks, NCS=8
      k_g6<8, true, true, EPI_PART><<<dim3(32, 8, 1), 256, 0, stream>>>(
          x2Hi, x2Lo, 4096, W2dHi, W2dLo, 4096, 4096, 128, partA, nullptr);
      // D4: LSTM2 epilogue (sums 8)
      k_epi2<<<512, 256, 0, stream>>>(partA, b2P, c2,
          xcH, xcL, xnH, xnL, h2nHi, h2nLo, lengths, t);
    }
  }
}